// Round 1
// baseline (1247.152 us; speedup 1.0000x reference)
//
#include <hip/hip_runtime.h>
#include <hip/hip_bf16.h>
#include <stdint.h>
#include <stddef.h>

// Problem constants
#define DIM    4096      // EMBED_DIM == OUT_FEATURES == in_features
#define MROWS  8192      // B*S = 4*2048
#define NCW    16384
#define NTILES 4
#define RPT    1024      // rows per tile

#define BM 128
#define BN 128
#define BK 32

typedef __attribute__((ext_vector_type(8))) short bf16x8;
typedef __attribute__((ext_vector_type(4))) float f32x4;

__device__ __forceinline__ uint16_t f2bf(float f) {
  union { float f; uint32_t u; } a; a.f = f;
  uint32_t u = a.u;
  u += 0x7fffu + ((u >> 16) & 1u);   // RTNE
  return (uint16_t)(u >> 16);
}

__device__ __forceinline__ void gl2lds16(const void* g, void* l) {
  __builtin_amdgcn_global_load_lds(
      (const __attribute__((address_space(1))) void*)g,
      (__attribute__((address_space(3))) void*)l, 16, 0, 0);
}

// ---------------------------------------------------------------------------
// Detect whether the 4096 indices arrived as int64 (odd dwords all zero) or
// int32. Writes 1 (int64) / 0 (int32) into *flag. Runs every launch.
// ---------------------------------------------------------------------------
__global__ void detect_idx_kernel(const uint32_t* __restrict__ inds,
                                  int* __restrict__ flag) {
  __shared__ int bad;
  if (threadIdx.x == 0) bad = 0;
  __syncthreads();
  int viol = 0;
  for (int k = threadIdx.x; k < 2048; k += 256) {
    uint32_t lo = inds[2 * k];
    uint32_t hi = inds[2 * k + 1];
    if (hi != 0u || lo >= (uint32_t)NCW) viol = 1;
  }
  if (viol) atomicAdd(&bad, 1);
  __syncthreads();
  if (threadIdx.x == 0) flag[0] = (bad == 0) ? 1 : 0;
}

// ---------------------------------------------------------------------------
// x fp32 -> bf16, 8 elems/thread, fully coalesced.
// ---------------------------------------------------------------------------
__global__ void cvt_x_kernel(const float* __restrict__ in,
                             uint16_t* __restrict__ out) {
  size_t i = ((size_t)blockIdx.x * 256 + threadIdx.x) * 8;
  float4 v0 = *(const float4*)(in + i);
  float4 v1 = *(const float4*)(in + i + 4);
  uint4 o;
  o.x = (uint32_t)f2bf(v0.x) | ((uint32_t)f2bf(v0.y) << 16);
  o.y = (uint32_t)f2bf(v0.z) | ((uint32_t)f2bf(v0.w) << 16);
  o.z = (uint32_t)f2bf(v1.x) | ((uint32_t)f2bf(v1.y) << 16);
  o.w = (uint32_t)f2bf(v1.z) | ((uint32_t)f2bf(v1.w) << 16);
  *(uint4*)(out + i) = o;
}

// ---------------------------------------------------------------------------
// Gather codeword rows by index, convert to bf16. One block per output row.
// ---------------------------------------------------------------------------
__global__ void gather_cw_kernel(const float* __restrict__ cw,
                                 const void* __restrict__ inds,
                                 const int* __restrict__ flag,
                                 uint16_t* __restrict__ out) {
  const int o = blockIdx.x;  // 0..4095
  long long idx;
  if (flag[0]) idx = ((const long long*)inds)[o];
  else         idx = (long long)((const int*)inds)[o];
  const float* src = cw + (size_t)idx * DIM;
  uint16_t* dst = out + (size_t)o * DIM;
  for (int c = 0; c < 4; c++) {
    int e = c * 1024 + threadIdx.x * 4;
    float4 v = *(const float4*)(src + e);
    uint2 w;
    w.x = (uint32_t)f2bf(v.x) | ((uint32_t)f2bf(v.y) << 16);
    w.y = (uint32_t)f2bf(v.z) | ((uint32_t)f2bf(v.w) << 16);
    *(uint2*)(dst + e) = w;
  }
}

// ---------------------------------------------------------------------------
// rotations[t][d][e] fp32 -> Rt[t][e][d] bf16  (transposed so the decode GEMM
// is B^T-form: K contiguous). 32x32 tiles, LDS staging, +1 pad.
// ---------------------------------------------------------------------------
__global__ void rot_transpose_kernel(const float* __restrict__ R,
                                     uint16_t* __restrict__ Rt) {
  __shared__ float tile[32][33];
  const int t = blockIdx.z;
  const int e0 = blockIdx.x * 32;
  const int d0 = blockIdx.y * 32;
  const float* Rp = R + (size_t)t * DIM * DIM;
  uint16_t* Rtp = Rt + (size_t)t * DIM * DIM;
  for (int i = threadIdx.y; i < 32; i += 8)
    tile[i][threadIdx.x] = Rp[(size_t)(d0 + i) * DIM + (e0 + threadIdx.x)];
  __syncthreads();
  for (int i = threadIdx.y; i < 32; i += 8)
    Rtp[(size_t)(e0 + i) * DIM + (d0 + threadIdx.x)] = f2bf(tile[threadIdx.x][i]);
}

// ---------------------------------------------------------------------------
// bf16 GEMM, B^T input:  C[M,N] = A[M,K] @ B[N,K]^T   (m97 structure)
// 128x128 block tile, BK=32, 4 waves (2x2), each wave 64x64 = 4x4 MFMA tiles.
// MODE 0 (decode): B is per-tile (t = m0>>10), epilogue = *scales[t], bf16 out.
// MODE 1 (output): epilogue = +bias[col], fp32 out.
// ---------------------------------------------------------------------------
template <int MODE>
__global__ __launch_bounds__(256)
void gemm_bt(const uint16_t* __restrict__ A,
             const uint16_t* __restrict__ B,
             const float* __restrict__ sv,   // scales (MODE 0) or bias (MODE 1)
             void* __restrict__ Cout,
             int N, int K) {
  __shared__ uint16_t As[BM * BK];
  __shared__ uint16_t Bs[BN * BK];

  const int tid  = threadIdx.x;
  const int wave = tid >> 6;
  const int lane = tid & 63;
  const int quad = lane >> 4;
  const int lr   = lane & 15;
  const int wm   = (wave >> 1) * 64;
  const int wn   = (wave & 1) * 64;

  const int m0 = blockIdx.y * BM;
  const int n0 = blockIdx.x * BN;

  const uint16_t* Bp = B;
  float scale = 1.0f;
  if (MODE == 0) {
    int t = m0 >> 10;                       // 1024 rows per tile
    Bp = B + (size_t)t * (size_t)N * (size_t)K;
    scale = sv[t];
  }

  // staging: 8 chunks of 1 KiB per matrix; wave stages chunks {2w, 2w+1}
  const int srow = lane >> 2;               // 0..15 within chunk
  const int scol = (lane & 3) * 8;          // element col in [0,32)
  const int ca   = wave * 2;

  const uint16_t* Ag = A  + (size_t)(m0 + srow) * K + scol;
  const uint16_t* Bg = Bp + (size_t)(n0 + srow) * K + scol;

  f32x4 acc[4][4];
#pragma unroll
  for (int i = 0; i < 4; i++)
#pragma unroll
    for (int j = 0; j < 4; j++) acc[i][j] = f32x4{0.f, 0.f, 0.f, 0.f};

  for (int k0 = 0; k0 < K; k0 += BK) {
#pragma unroll
    for (int i = 0; i < 2; i++) {
      int c = ca + i;
      gl2lds16(Ag + (size_t)(c * 16) * K + k0, &As[c * 512]);
      gl2lds16(Bg + (size_t)(c * 16) * K + k0, &Bs[c * 512]);
    }
    __builtin_amdgcn_s_waitcnt(0);          // drain vmcnt before barrier
    __syncthreads();

    bf16x8 a[4], b[4];
#pragma unroll
    for (int mi = 0; mi < 4; mi++)
      a[mi] = *(const bf16x8*)&As[(wm + mi * 16 + lr) * BK + quad * 8];
#pragma unroll
    for (int ni = 0; ni < 4; ni++)
      b[ni] = *(const bf16x8*)&Bs[(wn + ni * 16 + lr) * BK + quad * 8];

#pragma unroll
    for (int mi = 0; mi < 4; mi++)
#pragma unroll
      for (int ni = 0; ni < 4; ni++)
        acc[mi][ni] = __builtin_amdgcn_mfma_f32_16x16x32_bf16(
            a[mi], b[ni], acc[mi][ni], 0, 0, 0);

    __syncthreads();
  }

  // epilogue — C/D layout: col = lane&15, row = quad*4 + reg
  if (MODE == 0) {
    uint16_t* C = (uint16_t*)Cout;
#pragma unroll
    for (int mi = 0; mi < 4; mi++)
#pragma unroll
      for (int ni = 0; ni < 4; ni++)
#pragma unroll
        for (int r = 0; r < 4; r++) {
          int row = m0 + wm + mi * 16 + quad * 4 + r;
          int col = n0 + wn + ni * 16 + lr;
          C[(size_t)row * N + col] = f2bf(acc[mi][ni][r] * scale);
        }
  } else {
    float* C = (float*)Cout;
#pragma unroll
    for (int mi = 0; mi < 4; mi++)
#pragma unroll
      for (int ni = 0; ni < 4; ni++)
#pragma unroll
        for (int r = 0; r < 4; r++) {
          int row = m0 + wm + mi * 16 + quad * 4 + r;
          int col = n0 + wn + ni * 16 + lr;
          C[(size_t)row * N + col] = acc[mi][ni][r] + sv[col];
        }
  }
}

// ---------------------------------------------------------------------------
extern "C" void kernel_launch(void* const* d_in, const int* in_sizes, int n_in,
                              void* d_out, int out_size, void* d_ws,
                              size_t ws_size, hipStream_t stream) {
  const float* x      = (const float*)d_in[0];
  const float* cw     = (const float*)d_in[1];
  const void*  inds   = d_in[2];
  const float* rot    = (const float*)d_in[3];
  const float* scales = (const float*)d_in[4];
  const float* bias   = (const float*)d_in[5];
  float* out = (float*)d_out;

  // workspace layout (256 MiB + 256 B)
  char* ws = (char*)d_ws;
  int*      flag = (int*)ws;                                   // 4 B (pad 256)
  uint16_t* Xb   = (uint16_t*)(ws + 256);                      // 64 MiB
  uint16_t* Cgb  = (uint16_t*)(ws + 256 + (size_t)64  * 1024 * 1024); // 32 MiB
  uint16_t* Rt   = (uint16_t*)(ws + 256 + (size_t)96  * 1024 * 1024); // 128 MiB
  uint16_t* Wb   = (uint16_t*)(ws + 256 + (size_t)224 * 1024 * 1024); // 32 MiB

  detect_idx_kernel<<<1, 256, 0, stream>>>((const uint32_t*)inds, flag);

  // x -> bf16 : 33,554,432 elems / 8 per thread / 256 per block = 16384 blocks
  cvt_x_kernel<<<16384, 256, 0, stream>>>(x, Xb);

  gather_cw_kernel<<<DIM, 256, 0, stream>>>(cw, inds, flag, Cgb);

  rot_transpose_kernel<<<dim3(DIM / 32, DIM / 32, NTILES), dim3(32, 8), 0,
                         stream>>>(rot, Rt);

  // decode: Wb[o,e] = scales[t] * sum_d Cgb[o,d] * Rt[t][e,d]
  gemm_bt<0><<<dim3(DIM / BN, DIM / BM), 256, 0, stream>>>(
      Cgb, Rt, scales, (void*)Wb, DIM, DIM);

  // out[m,o] = sum_e Xb[m,e] * Wb[o,e] + bias[o]
  gemm_bt<1><<<dim3(DIM / BN, MROWS / BM), 256, 0, stream>>>(
      Xb, Wb, bias, (void*)out, DIM, DIM);
}